// Round 1
// baseline (180.793 us; speedup 1.0000x reference)
//
#include <hip/hip_runtime.h>
#include <hip/hip_bf16.h>
#include <stdint.h>

// LSTM cell as one fused bf16 MFMA GEMM:
//   gates(8192 x 4096) = A(8192 x 2048) @ Bp(4096 x 2048)^T, fused LSTM epilogue.
// A = [x | h_prev] bf16.  Bp rows are gate-interleaved per 16 hidden units:
//   packed row r = (h/16)*64 + g*16 + (h%16)  ->  wave's 4 N-fragments = 4 gates of same h.

#define B_DIM 8192
#define I_DIM 1024
#define H_DIM 1024
#define K_DIM 2048   // I + H
#define N_DIM 4096   // 4 gates * H

typedef short bf16x8 __attribute__((ext_vector_type(8)));
typedef float f32x4 __attribute__((ext_vector_type(4)));

__device__ __forceinline__ unsigned short f2bf(float f) {
  unsigned int u = __float_as_uint(f);
  u += 0x7FFFu + ((u >> 16) & 1u);   // RNE
  return (unsigned short)(u >> 16);
}

// ---- pack A = [x | h_prev] -> bf16 row-major (B_DIM, K_DIM) ----
__global__ void pack_A_kernel(const float* __restrict__ x,
                              const float* __restrict__ h,
                              unsigned short* __restrict__ outA) {
  const int total = B_DIM * K_DIM / 8;
  for (int idx = blockIdx.x * blockDim.x + threadIdx.x; idx < total;
       idx += gridDim.x * blockDim.x) {
    int row = idx >> 8;              // K_DIM/8 = 256 chunks/row
    int col = (idx & 255) * 8;
    const float* src = (col < I_DIM) ? (x + (size_t)row * I_DIM + col)
                                     : (h + (size_t)row * H_DIM + (col - I_DIM));
    const float4* s4 = (const float4*)src;
    float4 v0 = s4[0], v1 = s4[1];
    bf16x8 o;
    o[0] = f2bf(v0.x); o[1] = f2bf(v0.y); o[2] = f2bf(v0.z); o[3] = f2bf(v0.w);
    o[4] = f2bf(v1.x); o[5] = f2bf(v1.y); o[6] = f2bf(v1.z); o[7] = f2bf(v1.w);
    *(bf16x8*)(outA + (size_t)idx * 8) = o;
  }
}

// ---- pack B: 8 weight mats -> bf16 (N_DIM, K_DIM), gate-interleaved rows ----
__global__ void pack_B_kernel(const float* __restrict__ Wxi, const float* __restrict__ Whi,
                              const float* __restrict__ Wxf, const float* __restrict__ Whf,
                              const float* __restrict__ Wxc, const float* __restrict__ Whc,
                              const float* __restrict__ Wxo, const float* __restrict__ Who,
                              unsigned short* __restrict__ outB) {
  const int total = N_DIM * K_DIM / 8;
  for (int idx = blockIdx.x * blockDim.x + threadIdx.x; idx < total;
       idx += gridDim.x * blockDim.x) {
    int r = idx >> 8;
    int k = (idx & 255) * 8;
    int g = (r >> 4) & 3;
    int h = ((r >> 6) << 4) | (r & 15);
    const float* base;
    if (k < I_DIM) {
      base = (g == 0) ? Wxi : (g == 1) ? Wxf : (g == 2) ? Wxc : Wxo;
      base += (size_t)h * I_DIM + k;
    } else {
      base = (g == 0) ? Whi : (g == 1) ? Whf : (g == 2) ? Whc : Who;
      base += (size_t)h * H_DIM + (k - I_DIM);
    }
    const float4* s4 = (const float4*)base;
    float4 v0 = s4[0], v1 = s4[1];
    bf16x8 o;
    o[0] = f2bf(v0.x); o[1] = f2bf(v0.y); o[2] = f2bf(v0.z); o[3] = f2bf(v0.w);
    o[4] = f2bf(v1.x); o[5] = f2bf(v1.y); o[6] = f2bf(v1.z); o[7] = f2bf(v1.w);
    *(bf16x8*)(outB + (size_t)idx * 8) = o;
  }
}

// ---- GEMM 128x128 tile, BK=64, 4 waves (2x2), fused LSTM epilogue ----
__launch_bounds__(256, 2)
__global__ void lstm_gemm_kernel(const unsigned short* __restrict__ A,
                                 const unsigned short* __restrict__ Bp,
                                 const float* __restrict__ c_prev,
                                 const float* __restrict__ bxi, const float* __restrict__ bhi,
                                 const float* __restrict__ bxf, const float* __restrict__ bhf,
                                 const float* __restrict__ bxc, const float* __restrict__ bhc,
                                 const float* __restrict__ bxo, const float* __restrict__ bho,
                                 float* __restrict__ out) {
  __shared__ __align__(16) char sA[128 * 64 * 2];
  __shared__ __align__(16) char sB[128 * 64 * 2];

  // XCD-aware bijective swizzle (2048 % 8 == 0)
  const int nwg = gridDim.x;
  int bid = blockIdx.x;
  int q = nwg >> 3;
  int wg = (bid & 7) * q + (bid >> 3);
  int bm = wg >> 5;          // 64 M-tiles
  int bn = wg & 31;          // 32 N-tiles

  int tid = threadIdx.x;
  int lane = tid & 63;
  int wid = tid >> 6;
  int wm = wid >> 1;
  int wn = wid & 1;

  // staging: per call, wave covers 8 rows x 64B(K). Pre-swizzled global source
  // (rule #21): linear LDS dest + src col-chunk XOR row&7 + same XOR on read.
  int srow = lane >> 3;                 // row within 8-row stripe
  int scol = (lane & 7) ^ srow;         // swizzled 16B chunk
  const unsigned short* gA = A + (size_t)(bm * 128 + wid * 8 + srow) * K_DIM + scol * 8;
  const unsigned short* gB = Bp + (size_t)(bn * 128 + wid * 8 + srow) * K_DIM + scol * 8;
  char* lA = sA + wid * 1024;           // wave-uniform LDS base (HW adds lane*16)
  char* lB = sB + wid * 1024;

  f32x4 acc[4][4];
  f32x4 zero = {0.f, 0.f, 0.f, 0.f};
#pragma unroll
  for (int m = 0; m < 4; ++m)
#pragma unroll
    for (int n = 0; n < 4; ++n) acc[m][n] = zero;

  int c15 = lane & 15;
  int kl = lane >> 4;                   // k-group 0..3
  int swz = (lane & 7) << 4;            // (row&7)<<4 on the read side
  int rAb = wm * 64 + c15;
  int rBb = wn * 64 + c15;

  for (int kt = 0; kt < K_DIM / 64; ++kt) {
#pragma unroll
    for (int i = 0; i < 4; ++i) {
      __builtin_amdgcn_global_load_lds(
          (const __attribute__((address_space(1))) void*)(gA + (size_t)i * 32 * K_DIM + kt * 64),
          (__attribute__((address_space(3))) void*)(lA + i * 4096), 16, 0, 0);
      __builtin_amdgcn_global_load_lds(
          (const __attribute__((address_space(1))) void*)(gB + (size_t)i * 32 * K_DIM + kt * 64),
          (__attribute__((address_space(3))) void*)(lB + i * 4096), 16, 0, 0);
    }
    asm volatile("s_waitcnt vmcnt(0)" ::: "memory");
    __syncthreads();

#pragma unroll
    for (int kk = 0; kk < 2; ++kk) {
      bf16x8 af[4], bfr[4];
#pragma unroll
      for (int m = 0; m < 4; ++m)
        af[m] = *(const bf16x8*)(sA + (rAb + m * 16) * 128 + ((((kk << 2) | kl) << 4) ^ swz));
#pragma unroll
      for (int n = 0; n < 4; ++n)
        bfr[n] = *(const bf16x8*)(sB + (rBb + n * 16) * 128 + ((((kk << 2) | kl) << 4) ^ swz));
#pragma unroll
      for (int m = 0; m < 4; ++m)
#pragma unroll
        for (int n = 0; n < 4; ++n)
          acc[m][n] = __builtin_amdgcn_mfma_f32_16x16x32_bf16(af[m], bfr[n], acc[m][n], 0, 0, 0);
    }
    __syncthreads();
  }

  // ---- fused LSTM epilogue: lane owns hidden unit h, all 4 gates in acc[m][g] ----
  int h = (bn * 2 + wn) * 16 + c15;
  float bi = bxi[h] + bhi[h];
  float bf_ = bxf[h] + bhf[h];
  float bc = bxc[h] + bhc[h];
  float bo = bxo[h] + bho[h];
  int row0 = bm * 128 + wm * 64 + kl * 4;
#pragma unroll
  for (int m = 0; m < 4; ++m) {
#pragma unroll
    for (int j = 0; j < 4; ++j) {
      int r = row0 + m * 16 + j;
      size_t off = (size_t)r * H_DIM + h;
      float zi = acc[m][0][j] + bi;
      float zf = acc[m][1][j] + bf_;
      float zc = acc[m][2][j] + bc;
      float zo = acc[m][3][j] + bo;
      float ig = 1.f / (1.f + __expf(-zi));
      float fg = 1.f / (1.f + __expf(-zf));
      float e2 = __expf(-2.f * zc);
      float gg = (1.f - e2) / (1.f + e2);       // tanh(zc)
      float og = 1.f / (1.f + __expf(-zo));
      float cp = c_prev[off];
      float cn = fg * cp + ig * gg;
      float e2c = __expf(-2.f * cn);
      float th = (1.f - e2c) / (1.f + e2c);     // tanh(cn)
      out[off] = og * th;                        // h_new
      out[(size_t)B_DIM * H_DIM + off] = cn;     // c_new
    }
  }
}

extern "C" void kernel_launch(void* const* d_in, const int* in_sizes, int n_in,
                              void* d_out, int out_size, void* d_ws, size_t ws_size,
                              hipStream_t stream) {
  const float* x      = (const float*)d_in[0];
  const float* h_prev = (const float*)d_in[1];
  const float* c_prev = (const float*)d_in[2];
  const float* Wxi = (const float*)d_in[3];
  const float* Whi = (const float*)d_in[4];
  const float* Wxf = (const float*)d_in[5];
  const float* Whf = (const float*)d_in[6];
  const float* Wxc = (const float*)d_in[7];
  const float* Whc = (const float*)d_in[8];
  const float* Wxo = (const float*)d_in[9];
  const float* Who = (const float*)d_in[10];
  const float* bxi = (const float*)d_in[11];
  const float* bhi = (const float*)d_in[12];
  const float* bxf = (const float*)d_in[13];
  const float* bhf = (const float*)d_in[14];
  const float* bxc = (const float*)d_in[15];
  const float* bhc = (const float*)d_in[16];
  const float* bxo = (const float*)d_in[17];
  const float* bho = (const float*)d_in[18];

  unsigned short* Abf = (unsigned short*)d_ws;                                  // 32 MiB
  unsigned short* Bbf = (unsigned short*)((char*)d_ws + (size_t)B_DIM * K_DIM * 2); // +16 MiB

  pack_A_kernel<<<2048, 256, 0, stream>>>(x, h_prev, Abf);
  pack_B_kernel<<<1024, 256, 0, stream>>>(Wxi, Whi, Wxf, Whf, Wxc, Whc, Wxo, Who, Bbf);
  lstm_gemm_kernel<<<2048, 256, 0, stream>>>(Abf, Bbf, c_prev,
      bxi, bhi, bxf, bhf, bxc, bhc, bxo, bho, (float*)d_out);
}

// Round 4
// 166.994 us; speedup vs baseline: 1.0826x; 1.0826x over previous
//
#include <hip/hip_runtime.h>
#include <hip/hip_bf16.h>
#include <stdint.h>

// LSTM cell as one fused bf16 MFMA GEMM (256x256 8-phase schedule, m201 template):
//   gates(8192 x 4096) = A(8192 x 2048) @ Bp(4096 x 2048)^T, fused LSTM epilogue.
// A = [x | h_prev] bf16.  Bp rows gate-interleaved per 16 hidden units:
//   packed row r = (h/16)*64 + g*16 + (h%16) -> wave's 4 N-frags = 4 gates of same h.
//
// ROUND 4: race-free stage placement. Each operand-half is ds-read exactly ONCE
// per K-tile (B-low held in registers across the tile); stages target a slot
// only AFTER its last read, barrier-separated:
//   P0: ds A-lo + B-lo | MFMA Q(0,0)                      (no stage)
//   P1: ds B-hi        | MFMA Q(0,1)                      (no stage)
//   P2: ds A-hi        | stage B0,B1(KT+2)->buf | MFMA Q(1,1)   [B slots' last read was P1]
//   P3: (regs only)    | stage A0,A1(KT+2)->buf | MFMA Q(1,0)   [A slots' last read was P2]
// End of tile: s_waitcnt vmcnt(8) = exactly this tile's 8 in-flight loads ->
// all older loads (KT+1 data) complete before next tile reads them.

#define B_DIM 8192
#define I_DIM 1024
#define H_DIM 1024
#define K_DIM 2048   // I + H
#define N_DIM 4096   // 4 gates * H
#define NKT   32     // K_DIM / 64

typedef short bf16x8 __attribute__((ext_vector_type(8)));
typedef float f32x4 __attribute__((ext_vector_type(4)));

__device__ __forceinline__ unsigned short f2bf(float f) {
  unsigned int u = __float_as_uint(f);
  u += 0x7FFFu + ((u >> 16) & 1u);   // RNE
  return (unsigned short)(u >> 16);
}

// ---- pack A = [x | h_prev] -> bf16 row-major (B_DIM, K_DIM) ----
__global__ void pack_A_kernel(const float* __restrict__ x,
                              const float* __restrict__ h,
                              unsigned short* __restrict__ outA) {
  const int total = B_DIM * K_DIM / 8;
  for (int idx = blockIdx.x * blockDim.x + threadIdx.x; idx < total;
       idx += gridDim.x * blockDim.x) {
    int row = idx >> 8;              // K_DIM/8 = 256 chunks/row
    int col = (idx & 255) * 8;
    const float* src = (col < I_DIM) ? (x + (size_t)row * I_DIM + col)
                                     : (h + (size_t)row * H_DIM + (col - I_DIM));
    const float4* s4 = (const float4*)src;
    float4 v0 = s4[0], v1 = s4[1];
    bf16x8 o;
    o[0] = f2bf(v0.x); o[1] = f2bf(v0.y); o[2] = f2bf(v0.z); o[3] = f2bf(v0.w);
    o[4] = f2bf(v1.x); o[5] = f2bf(v1.y); o[6] = f2bf(v1.z); o[7] = f2bf(v1.w);
    *(bf16x8*)(outA + (size_t)idx * 8) = o;
  }
}

// ---- pack B: 8 weight mats -> bf16 (N_DIM, K_DIM), gate-interleaved rows ----
__global__ void pack_B_kernel(const float* __restrict__ Wxi, const float* __restrict__ Whi,
                              const float* __restrict__ Wxf, const float* __restrict__ Whf,
                              const float* __restrict__ Wxc, const float* __restrict__ Whc,
                              const float* __restrict__ Wxo, const float* __restrict__ Who,
                              unsigned short* __restrict__ outB) {
  const int total = N_DIM * K_DIM / 8;
  for (int idx = blockIdx.x * blockDim.x + threadIdx.x; idx < total;
       idx += gridDim.x * blockDim.x) {
    int r = idx >> 8;
    int k = (idx & 255) * 8;
    int g = (r >> 4) & 3;
    int h = ((r >> 6) << 4) | (r & 15);
    const float* base;
    if (k < I_DIM) {
      base = (g == 0) ? Wxi : (g == 1) ? Wxf : (g == 2) ? Wxc : Wxo;
      base += (size_t)h * I_DIM + k;
    } else {
      base = (g == 0) ? Whi : (g == 1) ? Whf : (g == 2) ? Whc : Who;
      base += (size_t)h * H_DIM + (k - I_DIM);
    }
    const float4* s4 = (const float4*)base;
    float4 v0 = s4[0], v1 = s4[1];
    bf16x8 o;
    o[0] = f2bf(v0.x); o[1] = f2bf(v0.y); o[2] = f2bf(v0.z); o[3] = f2bf(v0.w);
    o[4] = f2bf(v1.x); o[5] = f2bf(v1.y); o[6] = f2bf(v1.z); o[7] = f2bf(v1.w);
    *(bf16x8*)(outB + (size_t)idx * 8) = o;
  }
}

// ---- GEMM 256x256 tile, BK=64, 8 waves (2Mx4N), 8-phase counted-vmcnt ----
// LDS map (bytes): sA[buf][half] = buf*32768 + half*16384            (0..65536)
//                  sB[buf][half] = 65536 + buf*32768 + half*16384    (65536..131072)
// Half-tile = 128 rows x 64 cols bf16 = 16KB. KTILE(BUF,KT) stages all 4
// half-tiles of KT+2 into buf BUF (same parity). ktile index clamped so every
// tile issues exactly 8 loads (uniform vmcnt arithmetic; tail dupes are
// byte-identical or land in dead slots).

#define STAGE(gptr, slotoff, ktile) do {                                          \
    int _ktc = (ktile) < NKT ? (ktile) : (NKT - 1);                               \
    const unsigned short* _g = (gptr) + (size_t)_ktc * 64;                        \
    __builtin_amdgcn_global_load_lds(                                             \
        (const __attribute__((address_space(1))) void*)_g,                        \
        (__attribute__((address_space(3))) void*)(lds + (slotoff) + wid * 1024),  \
        16, 0, 0);                                                                \
    __builtin_amdgcn_global_load_lds(                                             \
        (const __attribute__((address_space(1))) void*)(_g + (size_t)64 * K_DIM), \
        (__attribute__((address_space(3))) void*)(lds + (slotoff) + 8192 + wid * 1024), \
        16, 0, 0);                                                                \
  } while (0)

#define MFMAQ(MH, GH, BARR)                                                       \
  _Pragma("unroll") for (int m = 0; m < 4; ++m)                                   \
  _Pragma("unroll") for (int nn = 0; nn < 2; ++nn)                                \
  _Pragma("unroll") for (int kk = 0; kk < 2; ++kk)                                \
    acc[(MH)*4 + m][(GH)*2 + nn] = __builtin_amdgcn_mfma_f32_16x16x32_bf16(       \
        Af[m][kk], BARR[nn][kk], acc[(MH)*4 + m][(GH)*2 + nn], 0, 0, 0)

#define KTILE(BUF, KT) do {                                                       \
    const int _bo = (BUF) * 32768;                                                \
    /* pre-P0: A-low + B-low (B-low held in regs through P3) */                   \
    _Pragma("unroll") for (int m = 0; m < 4; ++m) {                               \
      Af[m][0] = *(const bf16x8*)(ldsAr + _bo + m * 2048 + rd0);                  \
      Af[m][1] = *(const bf16x8*)(ldsAr + _bo + m * 2048 + rd1); }                \
    _Pragma("unroll") for (int nn = 0; nn < 2; ++nn) {                            \
      Bl[nn][0] = *(const bf16x8*)(ldsBr + _bo + nn * 2048 + rd0);                \
      Bl[nn][1] = *(const bf16x8*)(ldsBr + _bo + nn * 2048 + rd1); }              \
    __builtin_amdgcn_s_barrier();                                                 \
    asm volatile("s_waitcnt lgkmcnt(0)");                                         \
    __builtin_amdgcn_s_setprio(1);                                                \
    MFMAQ(0, 0, Bl);                                                              \
    __builtin_amdgcn_s_setprio(0);                                                \
    __builtin_amdgcn_s_barrier();                                                 \
    /* pre-P1: B-high */                                                          \
    _Pragma("unroll") for (int nn = 0; nn < 2; ++nn) {                            \
      Bh[nn][0] = *(const bf16x8*)(ldsBr + _bo + 4096 + nn * 2048 + rd0);         \
      Bh[nn][1] = *(const bf16x8*)(ldsBr + _bo + 4096 + nn * 2048 + rd1); }       \
    __builtin_amdgcn_s_barrier();                                                 \
    asm volatile("s_waitcnt lgkmcnt(0)");                                         \
    __builtin_amdgcn_s_setprio(1);                                                \
    MFMAQ(0, 1, Bh);                                                              \
    __builtin_amdgcn_s_setprio(0);                                                \
    __builtin_amdgcn_s_barrier();                                                 \
    /* pre-P2: A-high; stage B(KT+2) (B slots' last read was pre-P1) */           \
    _Pragma("unroll") for (int m = 0; m < 4; ++m) {                               \
      Af[m][0] = *(const bf16x8*)(ldsAr + _bo + 8192 + m * 2048 + rd0);           \
      Af[m][1] = *(const bf16x8*)(ldsAr + _bo + 8192 + m * 2048 + rd1); }         \
    STAGE(gB0p, 65536 + _bo, (KT) + 2);                                           \
    STAGE(gB1p, 65536 + _bo + 16384, (KT) + 2);                                   \
    __builtin_amdgcn_s_barrier();                                                 \
    asm volatile("s_waitcnt lgkmcnt(0)");                                         \
    __builtin_amdgcn_s_setprio(1);                                                \
    MFMAQ(1, 1, Bh);                                                              \
    __builtin_amdgcn_s_setprio(0);                                                \
    __builtin_amdgcn_s_barrier();                                                 \
    /* pre-P3: stage A(KT+2) (A slots' last read was pre-P2) */                   \
    STAGE(gA0p, _bo, (KT) + 2);                                                   \
    STAGE(gA1p, _bo + 16384, (KT) + 2);                                           \
    __builtin_amdgcn_s_barrier();                                                 \
    __builtin_amdgcn_s_setprio(1);                                                \
    MFMAQ(1, 0, Bl);                                                              \
    __builtin_amdgcn_s_setprio(0);                                                \
    asm volatile("s_waitcnt vmcnt(8)" ::: "memory");                              \
    __builtin_amdgcn_s_barrier();                                                 \
  } while (0)

__launch_bounds__(512, 2)
__global__ void lstm_gemm_kernel(const unsigned short* __restrict__ A,
                                 const unsigned short* __restrict__ Bp,
                                 const float* __restrict__ c_prev,
                                 const float* __restrict__ bxi, const float* __restrict__ bhi,
                                 const float* __restrict__ bxf, const float* __restrict__ bhf,
                                 const float* __restrict__ bxc, const float* __restrict__ bhc,
                                 const float* __restrict__ bxo, const float* __restrict__ bho,
                                 float* __restrict__ out) {
  __shared__ __align__(16) char lds[131072];

  // XCD-aware bijective swizzle (512 % 8 == 0)
  const int nwg = gridDim.x;
  int bid = blockIdx.x;
  int q = nwg >> 3;
  int wg = (bid & 7) * q + (bid >> 3);
  int bm = wg >> 4;          // 32 M-tiles
  int bn = wg & 15;          // 16 N-tiles

  int tid = threadIdx.x;
  int lane = tid & 63;
  int wid = tid >> 6;        // 8 waves
  int wm = wid >> 2;         // 2 M-wave rows (128 rows each)
  int wn = wid & 3;          // 4 N-wave cols (64 cols each)

  // staging addresses: per half-tile, wave covers 8 rows x 128B; pre-swizzled
  // global source (rule #21): linear LDS dest, src chunk XOR row&7, same XOR on read.
  int srow = lane >> 3;                 // row within 8-row stripe
  int schunk = (lane & 7) ^ srow;       // swizzled 16B chunk
  const unsigned short* gA0p = A  + (size_t)(bm * 256 + wid * 8 + srow) * K_DIM + schunk * 8;
  const unsigned short* gA1p = gA0p + (size_t)128 * K_DIM;
  const unsigned short* gB0p = Bp + (size_t)(bn * 256 + wid * 8 + srow) * K_DIM + schunk * 8;
  const unsigned short* gB1p = gB0p + (size_t)128 * K_DIM;

  // LDS read bases (byte ptrs); frag row&7 == lane&7 for all fragment rows.
  int c15 = lane & 15;
  int kl = lane >> 4;                   // k-group 0..3
  const char* ldsAr = lds + wm * 16384 + c15 * 128;
  const char* ldsBr = lds + 65536 + (wn >> 1) * 16384 + ((wn & 1) * 64 + c15) * 128;
  int rd0 = ((kl) ^ (lane & 7)) << 4;         // kk=0 chunk
  int rd1 = ((4 | kl) ^ (lane & 7)) << 4;     // kk=1 chunk

  f32x4 acc[8][4];
  f32x4 zero = {0.f, 0.f, 0.f, 0.f};
#pragma unroll
  for (int m = 0; m < 8; ++m)
#pragma unroll
    for (int n = 0; n < 4; ++n) acc[m][n] = zero;

  bf16x8 Af[4][2];   // A fragments (low half, then overwritten by high half)
  bf16x8 Bl[2][2];   // B-low  (gates 0,1) — live P0..P3
  bf16x8 Bh[2][2];   // B-high (gates 2,3) — live P1..P2

  // ---- prologue: stage kt0 -> buf0 (8 loads), kt1 -> buf1 (8 loads);
  // vmcnt(8) -> kt0's 8 loads complete. ----
  STAGE(gA0p, 0, 0);
  STAGE(gA1p, 16384, 0);
  STAGE(gB0p, 65536, 0);
  STAGE(gB1p, 65536 + 16384, 0);
  STAGE(gA0p, 32768, 1);
  STAGE(gA1p, 32768 + 16384, 1);
  STAGE(gB0p, 65536 + 32768, 1);
  STAGE(gB1p, 65536 + 32768 + 16384, 1);
  asm volatile("s_waitcnt vmcnt(8)" ::: "memory");
  __builtin_amdgcn_s_barrier();

#pragma unroll 1
  for (int kt = 0; kt < NKT; kt += 2) {
    KTILE(0, kt);
    KTILE(1, kt + 1);
  }

  // ---- fused LSTM epilogue: lane owns hidden unit h; acc[mi][g][j] = gate g ----
  int h = (bn * 4 + wn) * 16 + c15;
  float bi = bxi[h] + bhi[h];
  float bf_ = bxf[h] + bhf[h];
  float bc = bxc[h] + bhc[h];
  float bo = bxo[h] + bho[h];
  int row0 = bm * 256 + wm * 128 + kl * 4;
#pragma unroll
  for (int mi = 0; mi < 8; ++mi) {
#pragma unroll
    for (int j = 0; j < 4; ++j) {
      int r = row0 + mi * 16 + j;
      size_t off = (size_t)r * H_DIM + h;
      float zi = acc[mi][0][j] + bi;
      float zf = acc[mi][1][j] + bf_;
      float zc = acc[mi][2][j] + bc;
      float zo = acc[mi][3][j] + bo;
      float ig = 1.f / (1.f + __expf(-zi));
      float fg = 1.f / (1.f + __expf(-zf));
      float e2 = __expf(-2.f * zc);
      float gg = (1.f - e2) / (1.f + e2);       // tanh(zc)
      float og = 1.f / (1.f + __expf(-zo));
      float cp = c_prev[off];
      float cn = fg * cp + ig * gg;
      float e2c = __expf(-2.f * cn);
      float th = (1.f - e2c) / (1.f + e2c);     // tanh(cn)
      out[off] = og * th;                        // h_new
      out[(size_t)B_DIM * H_DIM + off] = cn;     // c_new
    }
  }
}

extern "C" void kernel_launch(void* const* d_in, const int* in_sizes, int n_in,
                              void* d_out, int out_size, void* d_ws, size_t ws_size,
                              hipStream_t stream) {
  const float* x      = (const float*)d_in[0];
  const float* h_prev = (const float*)d_in[1];
  const float* c_prev = (const float*)d_in[2];
  const float* Wxi = (const float*)d_in[3];
  const float* Whi = (const float*)d_in[4];
  const float* Wxf = (const float*)d_in[5];
  const float* Whf = (const float*)d_in[6];
  const float* Wxc = (const float*)d_in[7];
  const float* Whc = (const float*)d_in[8];
  const float* Wxo = (const float*)d_in[9];
  const float* Who = (const float*)d_in[10];
  const float* bxi = (const float*)d_in[11];
  const float* bhi = (const float*)d_in[12];
  const float* bxf = (const float*)d_in[13];
  const float* bhf = (const float*)d_in[14];
  const float* bxc = (const float*)d_in[15];
  const float* bhc = (const float*)d_in[16];
  const float* bxo = (const float*)d_in[17];
  const float* bho = (const float*)d_in[18];

  unsigned short* Abf = (unsigned short*)d_ws;                                      // 32 MiB
  unsigned short* Bbf = (unsigned short*)((char*)d_ws + (size_t)B_DIM * K_DIM * 2); // +16 MiB

  pack_A_kernel<<<2048, 256, 0, stream>>>(x, h_prev, Abf);
  pack_B_kernel<<<1024, 256, 0, stream>>>(Wxi, Whi, Wxf, Whf, Wxc, Whc, Wxo, Who, Bbf);
  lstm_gemm_kernel<<<512, 512, 0, stream>>>(Abf, Bbf, c_prev,
      bxi, bhi, bxf, bhf, bxc, bhc, bxo, bho, (float*)d_out);
}

// Round 5
// 162.344 us; speedup vs baseline: 1.1136x; 1.0286x over previous
//
#include <hip/hip_runtime.h>
#include <hip/hip_bf16.h>
#include <stdint.h>

// LSTM cell as one fused bf16 MFMA GEMM (256x256 8-phase schedule, m201 template):
//   gates(8192 x 4096) = A(8192 x 2048) @ Bp(4096 x 2048)^T, fused LSTM epilogue.
// A = [x | h_prev] bf16.  Bp rows gate-interleaved per 16 hidden units:
//   packed row r = (h/16)*64 + g*16 + (h%16) -> wave's 4 N-frags = 4 gates of same h.
//
// ROUND 5: (a) drop explicit lgkmcnt(0) drains — all ds-reads are plain C++,
// so the compiler emits fine-grained lgkmcnt(N) that overlaps MFMA issue with
// read completion; (b) uniform 2 staging loads per phase:
//   P0: ds A-lo + B-lo | stage A0(KT+1)->buf^1 | MFMA Q(0,0)
//   P1: ds B-hi        | stage A1(KT+1)->buf^1 | MFMA Q(0,1)
//   P2: ds A-hi        | stage B0(KT+2)->buf   | MFMA Q(1,1)
//   P3: (regs only)    | stage B1(KT+2)->buf   | MFMA Q(1,0); vmcnt(4)
// Slot-safety: every stage lands >=1 barrier after the slot's last consume
// (each phase's reads are consumed by that phase's MFMA cluster before its
// closing barrier). vmcnt(4) at tile end: newest 4 = B(KT+2) stages (stay in
// flight); everything older (A(KT+1)@P0/P1, B(KT+1)@KT-1) guaranteed landed,
// which is exactly what tile KT+1 reads.

#define B_DIM 8192
#define I_DIM 1024
#define H_DIM 1024
#define K_DIM 2048   // I + H
#define N_DIM 4096   // 4 gates * H
#define NKT   32     // K_DIM / 64

typedef short bf16x8 __attribute__((ext_vector_type(8)));
typedef float f32x4 __attribute__((ext_vector_type(4)));

__device__ __forceinline__ unsigned short f2bf(float f) {
  unsigned int u = __float_as_uint(f);
  u += 0x7FFFu + ((u >> 16) & 1u);   // RNE
  return (unsigned short)(u >> 16);
}

// ---- pack A = [x | h_prev] -> bf16 row-major (B_DIM, K_DIM) ----
__global__ void pack_A_kernel(const float* __restrict__ x,
                              const float* __restrict__ h,
                              unsigned short* __restrict__ outA) {
  const int total = B_DIM * K_DIM / 8;
  for (int idx = blockIdx.x * blockDim.x + threadIdx.x; idx < total;
       idx += gridDim.x * blockDim.x) {
    int row = idx >> 8;              // K_DIM/8 = 256 chunks/row
    int col = (idx & 255) * 8;
    const float* src = (col < I_DIM) ? (x + (size_t)row * I_DIM + col)
                                     : (h + (size_t)row * H_DIM + (col - I_DIM));
    const float4* s4 = (const float4*)src;
    float4 v0 = s4[0], v1 = s4[1];
    bf16x8 o;
    o[0] = f2bf(v0.x); o[1] = f2bf(v0.y); o[2] = f2bf(v0.z); o[3] = f2bf(v0.w);
    o[4] = f2bf(v1.x); o[5] = f2bf(v1.y); o[6] = f2bf(v1.z); o[7] = f2bf(v1.w);
    *(bf16x8*)(outA + (size_t)idx * 8) = o;
  }
}

// ---- pack B: 8 weight mats -> bf16 (N_DIM, K_DIM), gate-interleaved rows ----
__global__ void pack_B_kernel(const float* __restrict__ Wxi, const float* __restrict__ Whi,
                              const float* __restrict__ Wxf, const float* __restrict__ Whf,
                              const float* __restrict__ Wxc, const float* __restrict__ Whc,
                              const float* __restrict__ Wxo, const float* __restrict__ Who,
                              unsigned short* __restrict__ outB) {
  const int total = N_DIM * K_DIM / 8;
  for (int idx = blockIdx.x * blockDim.x + threadIdx.x; idx < total;
       idx += gridDim.x * blockDim.x) {
    int r = idx >> 8;
    int k = (idx & 255) * 8;
    int g = (r >> 4) & 3;
    int h = ((r >> 6) << 4) | (r & 15);
    const float* base;
    if (k < I_DIM) {
      base = (g == 0) ? Wxi : (g == 1) ? Wxf : (g == 2) ? Wxc : Wxo;
      base += (size_t)h * I_DIM + k;
    } else {
      base = (g == 0) ? Whi : (g == 1) ? Whf : (g == 2) ? Whc : Who;
      base += (size_t)h * H_DIM + (k - I_DIM);
    }
    const float4* s4 = (const float4*)base;
    float4 v0 = s4[0], v1 = s4[1];
    bf16x8 o;
    o[0] = f2bf(v0.x); o[1] = f2bf(v0.y); o[2] = f2bf(v0.z); o[3] = f2bf(v0.w);
    o[4] = f2bf(v1.x); o[5] = f2bf(v1.y); o[6] = f2bf(v1.z); o[7] = f2bf(v1.w);
    *(bf16x8*)(outB + (size_t)idx * 8) = o;
  }
}

// ---- GEMM 256x256 tile, BK=64, 8 waves (2Mx4N), 8-phase counted-vmcnt ----
// LDS map (bytes): sA[buf][half] = buf*32768 + half*16384            (0..65536)
//                  sB[buf][half] = 65536 + buf*32768 + half*16384    (65536..131072)
// Half-tile = 128 rows x 64 cols bf16 = 16KB. ktile index clamped so every
// tile issues exactly 8 loads (uniform vmcnt arithmetic; tail dupes write
// byte-identical data or land in dead slots).

#define STAGE(gptr, slotoff, ktile) do {                                          \
    int _ktc = (ktile) < NKT ? (ktile) : (NKT - 1);                               \
    const unsigned short* _g = (gptr) + (size_t)_ktc * 64;                        \
    __builtin_amdgcn_global_load_lds(                                             \
        (const __attribute__((address_space(1))) void*)_g,                        \
        (__attribute__((address_space(3))) void*)(lds + (slotoff) + wid * 1024),  \
        16, 0, 0);                                                                \
    __builtin_amdgcn_global_load_lds(                                             \
        (const __attribute__((address_space(1))) void*)(_g + (size_t)64 * K_DIM), \
        (__attribute__((address_space(3))) void*)(lds + (slotoff) + 8192 + wid * 1024), \
        16, 0, 0);                                                                \
  } while (0)

#define MFMAQ(MH, GH, BARR)                                                       \
  _Pragma("unroll") for (int m = 0; m < 4; ++m)                                   \
  _Pragma("unroll") for (int nn = 0; nn < 2; ++nn)                                \
  _Pragma("unroll") for (int kk = 0; kk < 2; ++kk)                                \
    acc[(MH)*4 + m][(GH)*2 + nn] = __builtin_amdgcn_mfma_f32_16x16x32_bf16(       \
        Af[m][kk], BARR[nn][kk], acc[(MH)*4 + m][(GH)*2 + nn], 0, 0, 0)

#define KTILE(BUF, KT) do {                                                       \
    const int _bo = (BUF) * 32768;                                                \
    const int _bo1 = ((BUF) ^ 1) * 32768;                                         \
    /* pre-P0: ds A-lo + B-lo (B-lo held in regs through P3); stage A0(KT+1) */   \
    _Pragma("unroll") for (int m = 0; m < 4; ++m) {                               \
      Af[m][0] = *(const bf16x8*)(ldsAr + _bo + m * 2048 + rd0);                  \
      Af[m][1] = *(const bf16x8*)(ldsAr + _bo + m * 2048 + rd1); }                \
    _Pragma("unroll") for (int nn = 0; nn < 2; ++nn) {                            \
      Bl[nn][0] = *(const bf16x8*)(ldsBr + _bo + nn * 2048 + rd0);                \
      Bl[nn][1] = *(const bf16x8*)(ldsBr + _bo + nn * 2048 + rd1); }              \
    STAGE(gA0p, _bo1, (KT) + 1);                                                  \
    __builtin_amdgcn_s_barrier();                                                 \
    __builtin_amdgcn_s_setprio(1);                                                \
    MFMAQ(0, 0, Bl);                                                              \
    __builtin_amdgcn_s_setprio(0);                                                \
    __builtin_amdgcn_s_barrier();                                                 \
    /* pre-P1: ds B-hi; stage A1(KT+1) */                                         \
    _Pragma("unroll") for (int nn = 0; nn < 2; ++nn) {                            \
      Bh[nn][0] = *(const bf16x8*)(ldsBr + _bo + 4096 + nn * 2048 + rd0);         \
      Bh[nn][1] = *(const bf16x8*)(ldsBr + _bo + 4096 + nn * 2048 + rd1); }       \
    STAGE(gA1p, _bo1 + 16384, (KT) + 1);                                          \
    __builtin_amdgcn_s_barrier();                                                 \
    __builtin_amdgcn_s_setprio(1);                                                \
    MFMAQ(0, 1, Bh);                                                              \
    __builtin_amdgcn_s_setprio(0);                                                \
    __builtin_amdgcn_s_barrier();                                                 \
    /* pre-P2: ds A-hi; stage B0(KT+2) (B0 slot consumed by P1's MFMA) */         \
    _Pragma("unroll") for (int m = 0; m < 4; ++m) {                               \
      Af[m][0] = *(const bf16x8*)(ldsAr + _bo + 8192 + m * 2048 + rd0);           \
      Af[m][1] = *(const bf16x8*)(ldsAr + _bo + 8192 + m * 2048 + rd1); }         \
    STAGE(gB0p, 65536 + _bo, (KT) + 2);                                           \
    __builtin_amdgcn_s_barrier();                                                 \
    __builtin_amdgcn_s_setprio(1);                                                \
    MFMAQ(1, 1, Bh);                                                              \
    __builtin_amdgcn_s_setprio(0);                                                \
    __builtin_amdgcn_s_barrier();                                                 \
    /* pre-P3: regs only; stage B1(KT+2) */                                       \
    STAGE(gB1p, 65536 + _bo + 16384, (KT) + 2);                                   \
    __builtin_amdgcn_s_barrier();                                                 \
    __builtin_amdgcn_s_setprio(1);                                                \
    MFMAQ(1, 0, Bl);                                                              \
    __builtin_amdgcn_s_setprio(0);                                                \
    asm volatile("s_waitcnt vmcnt(4)" ::: "memory");                              \
    __builtin_amdgcn_s_barrier();                                                 \
  } while (0)

__launch_bounds__(512, 2)
__global__ void lstm_gemm_kernel(const unsigned short* __restrict__ A,
                                 const unsigned short* __restrict__ Bp,
                                 const float* __restrict__ c_prev,
                                 const float* __restrict__ bxi, const float* __restrict__ bhi,
                                 const float* __restrict__ bxf, const float* __restrict__ bhf,
                                 const float* __restrict__ bxc, const float* __restrict__ bhc,
                                 const float* __restrict__ bxo, const float* __restrict__ bho,
                                 float* __restrict__ out) {
  __shared__ __align__(16) char lds[131072];

  // XCD-aware bijective swizzle (512 % 8 == 0)
  const int nwg = gridDim.x;
  int bid = blockIdx.x;
  int q = nwg >> 3;
  int wg = (bid & 7) * q + (bid >> 3);
  int bm = wg >> 4;          // 32 M-tiles
  int bn = wg & 15;          // 16 N-tiles

  int tid = threadIdx.x;
  int lane = tid & 63;
  int wid = tid >> 6;        // 8 waves
  int wm = wid >> 2;         // 2 M-wave rows (128 rows each)
  int wn = wid & 3;          // 4 N-wave cols (64 cols each)

  // staging addresses: per half-tile, wave covers 8 rows x 128B; pre-swizzled
  // global source (rule #21): linear LDS dest, src chunk XOR row&7, same XOR on read.
  int srow = lane >> 3;                 // row within 8-row stripe
  int schunk = (lane & 7) ^ srow;       // swizzled 16B chunk
  const unsigned short* gA0p = A  + (size_t)(bm * 256 + wid * 8 + srow) * K_DIM + schunk * 8;
  const unsigned short* gA1p = gA0p + (size_t)128 * K_DIM;
  const unsigned short* gB0p = Bp + (size_t)(bn * 256 + wid * 8 + srow) * K_DIM + schunk * 8;
  const unsigned short* gB1p = gB0p + (size_t)128 * K_DIM;

  // LDS read bases (byte ptrs); frag row&7 == lane&7 for all fragment rows.
  int c15 = lane & 15;
  int kl = lane >> 4;                   // k-group 0..3
  const char* ldsAr = lds + wm * 16384 + c15 * 128;
  const char* ldsBr = lds + 65536 + (wn >> 1) * 16384 + ((wn & 1) * 64 + c15) * 128;
  int rd0 = ((kl) ^ (lane & 7)) << 4;         // kk=0 chunk
  int rd1 = ((4 | kl) ^ (lane & 7)) << 4;     // kk=1 chunk

  f32x4 acc[8][4];
  f32x4 zero = {0.f, 0.f, 0.f, 0.f};
#pragma unroll
  for (int m = 0; m < 8; ++m)
#pragma unroll
    for (int n = 0; n < 4; ++n) acc[m][n] = zero;

  bf16x8 Af[4][2];   // A fragments (low half, then overwritten by high half)
  bf16x8 Bl[2][2];   // B-low  (gates 0,1) — live P0..P3
  bf16x8 Bh[2][2];   // B-high (gates 2,3) — live P1..P2

  // ---- prologue: stage A(0),B(0) -> buf0 (8 loads), B(1) -> buf1 (4 loads);
  // vmcnt(4) -> A(0),B(0) landed, B(1) in flight (steady-state entry). ----
  STAGE(gA0p, 0, 0);
  STAGE(gA1p, 16384, 0);
  STAGE(gB0p, 65536, 0);
  STAGE(gB1p, 65536 + 16384, 0);
  STAGE(gB0p, 65536 + 32768, 1);
  STAGE(gB1p, 65536 + 32768 + 16384, 1);
  asm volatile("s_waitcnt vmcnt(4)" ::: "memory");
  __builtin_amdgcn_s_barrier();

#pragma unroll 1
  for (int kt = 0; kt < NKT; kt += 2) {
    KTILE(0, kt);
    KTILE(1, kt + 1);
  }

  // ---- fused LSTM epilogue: lane owns hidden unit h; acc[mi][g][j] = gate g ----
  int h = (bn * 4 + wn) * 16 + c15;
  float bi = bxi[h] + bhi[h];
  float bf_ = bxf[h] + bhf[h];
  float bc = bxc[h] + bhc[h];
  float bo = bxo[h] + bho[h];
  int row0 = bm * 256 + wm * 128 + kl * 4;
#pragma unroll
  for (int mi = 0; mi < 8; ++mi) {
#pragma unroll
    for (int j = 0; j < 4; ++j) {
      int r = row0 + mi * 16 + j;
      size_t off = (size_t)r * H_DIM + h;
      float zi = acc[mi][0][j] + bi;
      float zf = acc[mi][1][j] + bf_;
      float zc = acc[mi][2][j] + bc;
      float zo = acc[mi][3][j] + bo;
      float ig = 1.f / (1.f + __expf(-zi));
      float fg = 1.f / (1.f + __expf(-zf));
      float e2 = __expf(-2.f * zc);
      float gg = (1.f - e2) / (1.f + e2);       // tanh(zc)
      float og = 1.f / (1.f + __expf(-zo));
      float cp = c_prev[off];
      float cn = fg * cp + ig * gg;
      float e2c = __expf(-2.f * cn);
      float th = (1.f - e2c) / (1.f + e2c);     // tanh(cn)
      out[off] = og * th;                        // h_new
      out[(size_t)B_DIM * H_DIM + off] = cn;     // c_new
    }
  }
}

extern "C" void kernel_launch(void* const* d_in, const int* in_sizes, int n_in,
                              void* d_out, int out_size, void* d_ws, size_t ws_size,
                              hipStream_t stream) {
  const float* x      = (const float*)d_in[0];
  const float* h_prev = (const float*)d_in[1];
  const float* c_prev = (const float*)d_in[2];
  const float* Wxi = (const float*)d_in[3];
  const float* Whi = (const float*)d_in[4];
  const float* Wxf = (const float*)d_in[5];
  const float* Whf = (const float*)d_in[6];
  const float* Wxc = (const float*)d_in[7];
  const float* Whc = (const float*)d_in[8];
  const float* Wxo = (const float*)d_in[9];
  const float* Who = (const float*)d_in[10];
  const float* bxi = (const float*)d_in[11];
  const float* bhi = (const float*)d_in[12];
  const float* bxf = (const float*)d_in[13];
  const float* bhf = (const float*)d_in[14];
  const float* bxc = (const float*)d_in[15];
  const float* bhc = (const float*)d_in[16];
  const float* bxo = (const float*)d_in[17];
  const float* bho = (const float*)d_in[18];

  unsigned short* Abf = (unsigned short*)d_ws;                                      // 32 MiB
  unsigned short* Bbf = (unsigned short*)((char*)d_ws + (size_t)B_DIM * K_DIM * 2); // +16 MiB

  pack_A_kernel<<<2048, 256, 0, stream>>>(x, h_prev, Abf);
  pack_B_kernel<<<1024, 256, 0, stream>>>(Wxi, Whi, Wxf, Whf, Wxc, Whc, Wxo, Who, Bbf);
  lstm_gemm_kernel<<<512, 512, 0, stream>>>(Abf, Bbf, c_prev,
      bxi, bhi, bxf, bhf, bxc, bhc, bxo, bho, (float*)d_out);
}

// Round 6
// 160.722 us; speedup vs baseline: 1.1249x; 1.0101x over previous
//
#include <hip/hip_runtime.h>
#include <hip/hip_bf16.h>
#include <stdint.h>

// LSTM cell as one fused bf16 MFMA GEMM (256x256 8-phase schedule):
//   gates(8192 x 4096) = A(8192 x 2048) @ Bp(4096 x 2048)^T, fused LSTM epilogue.
// A = [x | h_prev] bf16.  Bp rows gate-interleaved per 16 hidden units:
//   packed row r = (h/16)*64 + g*16 + (h%16) -> wave's 4 N-frags = 4 gates of same h.
//
// ROUND 6: register-level software pipeline (m196 "fine interleave" lever).
// Full-B frags read once at tile top; A quartered along M with AX/AY register
// double-buffer so each phase's MFMA consumes fragments read ONE PHASE EARLIER:
//   top: read Bf(8) + AX=q0(4) + AY=q1(4); stage A0(T+1); barrier
//   P0:  MFMA(q0,AX); barrier | read AX=q2; stage A1(T+1); barrier
//   P1:  MFMA(q1,AY); barrier | read AY=q3; stage B0(T+2); barrier
//   P2:  MFMA(q2,AX); barrier | stage B1(T+2); barrier
//   P3:  MFMA(q3,AY); vmcnt(4); barrier
// Only the tile-top read burst is latency-exposed (1x/tile instead of 4x).
// Frag regs: Bf 32 + AX 16 + AY 16 = 64 VGPR — identical footprint to round 5.
// Slot-safety: A slots read thru P2 -> A(T+1) staged @P0/P1 into buf^1 (last
// read = T-1's P2, >=3 barriers earlier). B slots read only at tile top ->
// B(T+2) staged @P2/P3 into buf (>=2 barriers after top). In-order vmcnt(4)
// at tile end => A(T+1) and B(T+1) landed before T+1 reads them.

#define B_DIM 8192
#define I_DIM 1024
#define H_DIM 1024
#define K_DIM 2048   // I + H
#define N_DIM 4096   // 4 gates * H
#define NKT   32     // K_DIM / 64

typedef short bf16x8 __attribute__((ext_vector_type(8)));
typedef float f32x4 __attribute__((ext_vector_type(4)));

__device__ __forceinline__ unsigned short f2bf(float f) {
  unsigned int u = __float_as_uint(f);
  u += 0x7FFFu + ((u >> 16) & 1u);   // RNE
  return (unsigned short)(u >> 16);
}

// ---- pack A = [x | h_prev] -> bf16 row-major (B_DIM, K_DIM) ----
__global__ void pack_A_kernel(const float* __restrict__ x,
                              const float* __restrict__ h,
                              unsigned short* __restrict__ outA) {
  const int total = B_DIM * K_DIM / 8;
  for (int idx = blockIdx.x * blockDim.x + threadIdx.x; idx < total;
       idx += gridDim.x * blockDim.x) {
    int row = idx >> 8;              // K_DIM/8 = 256 chunks/row
    int col = (idx & 255) * 8;
    const float* src = (col < I_DIM) ? (x + (size_t)row * I_DIM + col)
                                     : (h + (size_t)row * H_DIM + (col - I_DIM));
    const float4* s4 = (const float4*)src;
    float4 v0 = s4[0], v1 = s4[1];
    bf16x8 o;
    o[0] = f2bf(v0.x); o[1] = f2bf(v0.y); o[2] = f2bf(v0.z); o[3] = f2bf(v0.w);
    o[4] = f2bf(v1.x); o[5] = f2bf(v1.y); o[6] = f2bf(v1.z); o[7] = f2bf(v1.w);
    *(bf16x8*)(outA + (size_t)idx * 8) = o;
  }
}

// ---- pack B: 8 weight mats -> bf16 (N_DIM, K_DIM), gate-interleaved rows ----
__global__ void pack_B_kernel(const float* __restrict__ Wxi, const float* __restrict__ Whi,
                              const float* __restrict__ Wxf, const float* __restrict__ Whf,
                              const float* __restrict__ Wxc, const float* __restrict__ Whc,
                              const float* __restrict__ Wxo, const float* __restrict__ Who,
                              unsigned short* __restrict__ outB) {
  const int total = N_DIM * K_DIM / 8;
  for (int idx = blockIdx.x * blockDim.x + threadIdx.x; idx < total;
       idx += gridDim.x * blockDim.x) {
    int r = idx >> 8;
    int k = (idx & 255) * 8;
    int g = (r >> 4) & 3;
    int h = ((r >> 6) << 4) | (r & 15);
    const float* base;
    if (k < I_DIM) {
      base = (g == 0) ? Wxi : (g == 1) ? Wxf : (g == 2) ? Wxc : Wxo;
      base += (size_t)h * I_DIM + k;
    } else {
      base = (g == 0) ? Whi : (g == 1) ? Whf : (g == 2) ? Whc : Who;
      base += (size_t)h * H_DIM + (k - I_DIM);
    }
    const float4* s4 = (const float4*)base;
    float4 v0 = s4[0], v1 = s4[1];
    bf16x8 o;
    o[0] = f2bf(v0.x); o[1] = f2bf(v0.y); o[2] = f2bf(v0.z); o[3] = f2bf(v0.w);
    o[4] = f2bf(v1.x); o[5] = f2bf(v1.y); o[6] = f2bf(v1.z); o[7] = f2bf(v1.w);
    *(bf16x8*)(outB + (size_t)idx * 8) = o;
  }
}

// ---- GEMM 256x256 tile, BK=64, 8 waves (2Mx4N), 8-phase counted-vmcnt ----
// LDS map (bytes): sA[buf][half] = buf*32768 + half*16384            (0..65536)
//                  sB[buf][half] = 65536 + buf*32768 + half*16384    (65536..131072)
// Half-tile = 128 rows x 64 cols bf16 = 16KB. ktile index clamped so every
// tile issues exactly 8 loads (uniform vmcnt arithmetic; tail dupes write
// byte-identical data or land in dead slots).

#define STAGE(gptr, slotoff, ktile) do {                                          \
    int _ktc = (ktile) < NKT ? (ktile) : (NKT - 1);                               \
    const unsigned short* _g = (gptr) + (size_t)_ktc * 64;                        \
    __builtin_amdgcn_global_load_lds(                                             \
        (const __attribute__((address_space(1))) void*)_g,                        \
        (__attribute__((address_space(3))) void*)(lds + (slotoff) + wid * 1024),  \
        16, 0, 0);                                                                \
    __builtin_amdgcn_global_load_lds(                                             \
        (const __attribute__((address_space(1))) void*)(_g + (size_t)64 * K_DIM), \
        (__attribute__((address_space(3))) void*)(lds + (slotoff) + 8192 + wid * 1024), \
        16, 0, 0);                                                                \
  } while (0)

// phase Q (0..3) computes acc rows 2Q..2Q+1 (A rows waveslab + Q*32..+32)
#define MFMAQ(Q, AR)                                                              \
  _Pragma("unroll") for (int mq = 0; mq < 2; ++mq)                                \
  _Pragma("unroll") for (int nn = 0; nn < 4; ++nn)                                \
  _Pragma("unroll") for (int kk = 0; kk < 2; ++kk)                                \
    acc[(Q)*2 + mq][nn] = __builtin_amdgcn_mfma_f32_16x16x32_bf16(                \
        AR[mq][kk], Bf[nn][kk], acc[(Q)*2 + mq][nn], 0, 0, 0)

#define RD_A(DST, Q)                                                              \
  _Pragma("unroll") for (int mq = 0; mq < 2; ++mq) {                              \
    DST[mq][0] = *(const bf16x8*)(ldsAr + _bo + (Q) * 4096 + mq * 2048 + rd0);    \
    DST[mq][1] = *(const bf16x8*)(ldsAr + _bo + (Q) * 4096 + mq * 2048 + rd1); }

#define KTILE(BUF, KT) do {                                                       \
    const int _bo = (BUF) * 32768;                                                \
    const int _bo1 = ((BUF) ^ 1) * 32768;                                         \
    /* tile top: full B (8 reads) + A-q0 -> AX + A-q1 -> AY; stage A0(T+1) */     \
    _Pragma("unroll") for (int nn = 0; nn < 4; ++nn) {                            \
      Bf[nn][0] = *(const bf16x8*)(ldsBr + _bo + nn * 2048 + rd0);                \
      Bf[nn][1] = *(const bf16x8*)(ldsBr + _bo + nn * 2048 + rd1); }              \
    RD_A(AX, 0);                                                                  \
    RD_A(AY, 1);                                                                  \
    STAGE(gA0p, _bo1, (KT) + 1);                                                  \
    __builtin_amdgcn_s_barrier();                                                 \
    __builtin_amdgcn_s_setprio(1);                                                \
    MFMAQ(0, AX);                                                                 \
    __builtin_amdgcn_s_setprio(0);                                                \
    __builtin_amdgcn_s_barrier();                                                 \
    /* P1 segment: refill AX with q2 (consumed next phase); stage A1(T+1) */      \
    RD_A(AX, 2);                                                                  \
    STAGE(gA1p, _bo1 + 16384, (KT) + 1);                                          \
    __builtin_amdgcn_s_barrier();                                                 \
    __builtin_amdgcn_s_setprio(1);                                                \
    MFMAQ(1, AY);                                                                 \
    __builtin_amdgcn_s_setprio(0);                                                \
    __builtin_amdgcn_s_barrier();                                                 \
    /* P2 segment: refill AY with q3; stage B0(T+2) (B slot last read: top) */    \
    RD_A(AY, 3);                                                                  \
    STAGE(gB0p, 65536 + _bo, (KT) + 2);                                           \
    __builtin_amdgcn_s_barrier();                                                 \
    __builtin_amdgcn_s_setprio(1);                                                \
    MFMAQ(2, AX);                                                                 \
    __builtin_amdgcn_s_setprio(0);                                                \
    __builtin_amdgcn_s_barrier();                                                 \
    /* P3 segment: stage B1(T+2) */                                               \
    STAGE(gB1p, 65536 + _bo + 16384, (KT) + 2);                                   \
    __builtin_amdgcn_s_barrier();                                                 \
    __builtin_amdgcn_s_setprio(1);                                                \
    MFMAQ(3, AY);                                                                 \
    __builtin_amdgcn_s_setprio(0);                                                \
    asm volatile("s_waitcnt vmcnt(4)" ::: "memory");                              \
    __builtin_amdgcn_s_barrier();                                                 \
  } while (0)

__launch_bounds__(512, 2)
__global__ void lstm_gemm_kernel(const unsigned short* __restrict__ A,
                                 const unsigned short* __restrict__ Bp,
                                 const float* __restrict__ c_prev,
                                 const float* __restrict__ bxi, const float* __restrict__ bhi,
                                 const float* __restrict__ bxf, const float* __restrict__ bhf,
                                 const float* __restrict__ bxc, const float* __restrict__ bhc,
                                 const float* __restrict__ bxo, const float* __restrict__ bho,
                                 float* __restrict__ out) {
  __shared__ __align__(16) char lds[131072];

  // XCD-aware bijective swizzle (512 % 8 == 0)
  const int nwg = gridDim.x;
  int bid = blockIdx.x;
  int q = nwg >> 3;
  int wg = (bid & 7) * q + (bid >> 3);
  int bm = wg >> 4;          // 32 M-tiles
  int bn = wg & 15;          // 16 N-tiles

  int tid = threadIdx.x;
  int lane = tid & 63;
  int wid = tid >> 6;        // 8 waves
  int wm = wid >> 2;         // 2 M-wave rows (128 rows each)
  int wn = wid & 3;          // 4 N-wave cols (64 cols each)

  // staging addresses: per half-tile, wave covers 8 rows x 128B; pre-swizzled
  // global source (rule #21): linear LDS dest, src chunk XOR row&7, same XOR on read.
  int srow = lane >> 3;                 // row within 8-row stripe
  int schunk = (lane & 7) ^ srow;       // swizzled 16B chunk
  const unsigned short* gA0p = A  + (size_t)(bm * 256 + wid * 8 + srow) * K_DIM + schunk * 8;
  const unsigned short* gA1p = gA0p + (size_t)128 * K_DIM;
  const unsigned short* gB0p = Bp + (size_t)(bn * 256 + wid * 8 + srow) * K_DIM + schunk * 8;
  const unsigned short* gB1p = gB0p + (size_t)128 * K_DIM;

  // LDS read bases (byte ptrs); frag row&7 == lane&7 for all fragment rows.
  int c15 = lane & 15;
  int kl = lane >> 4;                   // k-group 0..3
  const char* ldsAr = lds + wm * 16384 + c15 * 128;
  const char* ldsBr = lds + 65536 + (wn >> 1) * 16384 + ((wn & 1) * 64 + c15) * 128;
  int rd0 = ((kl) ^ (lane & 7)) << 4;         // kk=0 chunk
  int rd1 = ((4 | kl) ^ (lane & 7)) << 4;     // kk=1 chunk

  f32x4 acc[8][4];
  f32x4 zero = {0.f, 0.f, 0.f, 0.f};
#pragma unroll
  for (int m = 0; m < 8; ++m)
#pragma unroll
    for (int n = 0; n < 4; ++n) acc[m][n] = zero;

  bf16x8 Bf[4][2];   // full B for the tile (4 n-frags x 2 kk) — live all tile
  bf16x8 AX[2][2];   // A-quarter ping
  bf16x8 AY[2][2];   // A-quarter pong

  // ---- prologue: stage A(0),B(0) -> buf0 (8 loads), B(1) -> buf1 (4 loads);
  // vmcnt(4) -> A(0),B(0) landed, B(1) in flight (steady-state entry). ----
  STAGE(gA0p, 0, 0);
  STAGE(gA1p, 16384, 0);
  STAGE(gB0p, 65536, 0);
  STAGE(gB1p, 65536 + 16384, 0);
  STAGE(gB0p, 65536 + 32768, 1);
  STAGE(gB1p, 65536 + 32768 + 16384, 1);
  asm volatile("s_waitcnt vmcnt(4)" ::: "memory");
  __builtin_amdgcn_s_barrier();

#pragma unroll 1
  for (int kt = 0; kt < NKT; kt += 2) {
    KTILE(0, kt);
    KTILE(1, kt + 1);
  }

  // ---- fused LSTM epilogue: lane owns hidden unit h; acc[mi][g][j] = gate g ----
  int h = (bn * 4 + wn) * 16 + c15;
  float bi = bxi[h] + bhi[h];
  float bf_ = bxf[h] + bhf[h];
  float bc = bxc[h] + bhc[h];
  float bo = bxo[h] + bho[h];
  int row0 = bm * 256 + wm * 128 + kl * 4;
#pragma unroll
  for (int mi = 0; mi < 8; ++mi) {
#pragma unroll
    for (int j = 0; j < 4; ++j) {
      int r = row0 + mi * 16 + j;
      size_t off = (size_t)r * H_DIM + h;
      float zi = acc[mi][0][j] + bi;
      float zf = acc[mi][1][j] + bf_;
      float zc = acc[mi][2][j] + bc;
      float zo = acc[mi][3][j] + bo;
      float ig = 1.f / (1.f + __expf(-zi));
      float fg = 1.f / (1.f + __expf(-zf));
      float e2 = __expf(-2.f * zc);
      float gg = (1.f - e2) / (1.f + e2);       // tanh(zc)
      float og = 1.f / (1.f + __expf(-zo));
      float cp = c_prev[off];
      float cn = fg * cp + ig * gg;
      float e2c = __expf(-2.f * cn);
      float th = (1.f - e2c) / (1.f + e2c);     // tanh(cn)
      out[off] = og * th;                        // h_new
      out[(size_t)B_DIM * H_DIM + off] = cn;     // c_new
    }
  }
}

extern "C" void kernel_launch(void* const* d_in, const int* in_sizes, int n_in,
                              void* d_out, int out_size, void* d_ws, size_t ws_size,
                              hipStream_t stream) {
  const float* x      = (const float*)d_in[0];
  const float* h_prev = (const float*)d_in[1];
  const float* c_prev = (const float*)d_in[2];
  const float* Wxi = (const float*)d_in[3];
  const float* Whi = (const float*)d_in[4];
  const float* Wxf = (const float*)d_in[5];
  const float* Whf = (const float*)d_in[6];
  const float* Wxc = (const float*)d_in[7];
  const float* Whc = (const float*)d_in[8];
  const float* Wxo = (const float*)d_in[9];
  const float* Who = (const float*)d_in[10];
  const float* bxi = (const float*)d_in[11];
  const float* bhi = (const float*)d_in[12];
  const float* bxf = (const float*)d_in[13];
  const float* bhf = (const float*)d_in[14];
  const float* bxc = (const float*)d_in[15];
  const float* bhc = (const float*)d_in[16];
  const float* bxo = (const float*)d_in[17];
  const float* bho = (const float*)d_in[18];

  unsigned short* Abf = (unsigned short*)d_ws;                                      // 32 MiB
  unsigned short* Bbf = (unsigned short*)((char*)d_ws + (size_t)B_DIM * K_DIM * 2); // +16 MiB

  pack_A_kernel<<<2048, 256, 0, stream>>>(x, h_prev, Abf);
  pack_B_kernel<<<1024, 256, 0, stream>>>(Wxi, Whi, Wxf, Whf, Wxc, Whc, Wxo, Who, Bbf);
  lstm_gemm_kernel<<<512, 512, 0, stream>>>(Abf, Bbf, c_prev,
      bxi, bhi, bxf, bhf, bxc, bhc, bxo, bho, (float*)d_out);
}

// Round 7
// 153.598 us; speedup vs baseline: 1.1771x; 1.0464x over previous
//
#include <hip/hip_runtime.h>
#include <hip/hip_bf16.h>
#include <stdint.h>

// LSTM cell as one fused bf16 MFMA GEMM (256x256, 4-phase/K-tile, MFMA-first):
//   gates(8192 x 4096) = A(8192 x 2048) @ Bp(4096 x 2048)^T, fused LSTM epilogue.
// A = [x | h_prev] bf16.  Bp rows gate-interleaved per 16 hidden units:
//   packed row r = (h/16)*64 + g*16 + (h%16) -> wave's 4 N-frags = 4 gates of same h.
//
// ROUND 7: balance LDS-read traffic across phases + read one-phase-ahead.
// Phase (mh,kk) = 16 INDEPENDENT MFMAs (4m x 4n x 1kk) consuming an A-quarter
// (4 ds_read_b128) + B-kk-half (4 reads) read in the PREVIOUS phase (ping-pong
// regs AQa/AQb, BHa/BHb). MFMA-first phases, ONE barrier per phase:
//   p0: MFMA(mh0,AQa,BHa) | read AQb<-A(m1,k0)                      | bar
//   p1: MFMA(mh1,AQb,BHa) | read BHb<-B(k1), AQa<-A(m0,k1)          | bar
//   p2: MFMA(mh0,AQa,BHb) | read AQb<-A(m1,k1); stage B(T+2); vmcnt(4) | bar
//   p3: MFMA(mh1,AQb,BHb) | read AQa<-A(m0,k0,T+1), BHa<-B(k0,T+1); stage A(T+2) | bar
// Slot-safety per window (cross-wave): A slots of buf[T] read W3(T-1)..W2(T),
// staged @p3(T) for T+2 (>=1 bar after last read). B slots read W1(T), staged
// @p2(T). p3 reads buf[T+1] only; in-flight writes always target the other
// buffer or a slot past its last read. vmcnt(4) @p2-end leaves only B(T+2)'s
// 4 loads in flight -> A(T+1),B(T+1) landed before p3's cross-buffer reads.
// Tail: clamped ktile index keeps 8 loads/tile uniform (dupes land in dead
// slots or rewrite identical bytes).

#define B_DIM 8192
#define I_DIM 1024
#define H_DIM 1024
#define K_DIM 2048   // I + H
#define N_DIM 4096   // 4 gates * H
#define NKT   32     // K_DIM / 64

typedef short bf16x8 __attribute__((ext_vector_type(8)));
typedef float f32x4 __attribute__((ext_vector_type(4)));

__device__ __forceinline__ unsigned short f2bf(float f) {
  unsigned int u = __float_as_uint(f);
  u += 0x7FFFu + ((u >> 16) & 1u);   // RNE
  return (unsigned short)(u >> 16);
}

// ---- pack A = [x | h_prev] -> bf16 row-major (B_DIM, K_DIM) ----
__global__ void pack_A_kernel(const float* __restrict__ x,
                              const float* __restrict__ h,
                              unsigned short* __restrict__ outA) {
  const int total = B_DIM * K_DIM / 8;
  for (int idx = blockIdx.x * blockDim.x + threadIdx.x; idx < total;
       idx += gridDim.x * blockDim.x) {
    int row = idx >> 8;              // K_DIM/8 = 256 chunks/row
    int col = (idx & 255) * 8;
    const float* src = (col < I_DIM) ? (x + (size_t)row * I_DIM + col)
                                     : (h + (size_t)row * H_DIM + (col - I_DIM));
    const float4* s4 = (const float4*)src;
    float4 v0 = s4[0], v1 = s4[1];
    bf16x8 o;
    o[0] = f2bf(v0.x); o[1] = f2bf(v0.y); o[2] = f2bf(v0.z); o[3] = f2bf(v0.w);
    o[4] = f2bf(v1.x); o[5] = f2bf(v1.y); o[6] = f2bf(v1.z); o[7] = f2bf(v1.w);
    *(bf16x8*)(outA + (size_t)idx * 8) = o;
  }
}

// ---- pack B: 8 weight mats -> bf16 (N_DIM, K_DIM), gate-interleaved rows ----
__global__ void pack_B_kernel(const float* __restrict__ Wxi, const float* __restrict__ Whi,
                              const float* __restrict__ Wxf, const float* __restrict__ Whf,
                              const float* __restrict__ Wxc, const float* __restrict__ Whc,
                              const float* __restrict__ Wxo, const float* __restrict__ Who,
                              unsigned short* __restrict__ outB) {
  const int total = N_DIM * K_DIM / 8;
  for (int idx = blockIdx.x * blockDim.x + threadIdx.x; idx < total;
       idx += gridDim.x * blockDim.x) {
    int r = idx >> 8;
    int k = (idx & 255) * 8;
    int g = (r >> 4) & 3;
    int h = ((r >> 6) << 4) | (r & 15);
    const float* base;
    if (k < I_DIM) {
      base = (g == 0) ? Wxi : (g == 1) ? Wxf : (g == 2) ? Wxc : Wxo;
      base += (size_t)h * I_DIM + k;
    } else {
      base = (g == 0) ? Whi : (g == 1) ? Whf : (g == 2) ? Whc : Who;
      base += (size_t)h * H_DIM + (k - I_DIM);
    }
    const float4* s4 = (const float4*)base;
    float4 v0 = s4[0], v1 = s4[1];
    bf16x8 o;
    o[0] = f2bf(v0.x); o[1] = f2bf(v0.y); o[2] = f2bf(v0.z); o[3] = f2bf(v0.w);
    o[4] = f2bf(v1.x); o[5] = f2bf(v1.y); o[6] = f2bf(v1.z); o[7] = f2bf(v1.w);
    *(bf16x8*)(outB + (size_t)idx * 8) = o;
  }
}

// ---- GEMM 256x256 tile, BK=64, 8 waves (2Mx4N) ----
// LDS map (bytes): sA[buf][half] = buf*32768 + half*16384            (0..65536)
//                  sB[buf][half] = 65536 + buf*32768 + half*16384    (65536..131072)

#define STAGE(gptr, slotoff, ktile) do {                                          \
    int _ktc = (ktile) < NKT ? (ktile) : (NKT - 1);                               \
    const unsigned short* _g = (gptr) + (size_t)_ktc * 64;                        \
    __builtin_amdgcn_global_load_lds(                                             \
        (const __attribute__((address_space(1))) void*)_g,                        \
        (__attribute__((address_space(3))) void*)(lds + (slotoff) + wid * 1024),  \
        16, 0, 0);                                                                \
    __builtin_amdgcn_global_load_lds(                                             \
        (const __attribute__((address_space(1))) void*)(_g + (size_t)64 * K_DIM), \
        (__attribute__((address_space(3))) void*)(lds + (slotoff) + 8192 + wid * 1024), \
        16, 0, 0);                                                                \
  } while (0)

// phase (MH, kk): 16 independent MFMAs, acc rows MH*4..MH*4+3, one kk slice
#define MFMAP(MH, AR, BR)                                                         \
  _Pragma("unroll") for (int mf = 0; mf < 4; ++mf)                                \
  _Pragma("unroll") for (int nn = 0; nn < 4; ++nn)                                \
    acc[(MH)*4 + mf][nn] = __builtin_amdgcn_mfma_f32_16x16x32_bf16(               \
        AR[mf], BR[nn], acc[(MH)*4 + mf][nn], 0, 0, 0)

#define RD_AQ(DST, MH, KOFF, BO)                                                  \
  _Pragma("unroll") for (int mf = 0; mf < 4; ++mf)                                \
    DST[mf] = *(const bf16x8*)(ldsAr + (BO) + (MH)*8192 + mf * 2048 + (KOFF));

#define RD_BH(DST, KOFF, BO)                                                      \
  _Pragma("unroll") for (int nn = 0; nn < 4; ++nn)                                \
    DST[nn] = *(const bf16x8*)(ldsBr + (BO) + nn * 2048 + (KOFF));

#define KTILE(BUF, KT) do {                                                       \
    const int _bo = (BUF) * 32768;                                                \
    const int _bo1 = ((BUF) ^ 1) * 32768;                                         \
    /* p0 */                                                                      \
    __builtin_amdgcn_s_setprio(1);                                                \
    MFMAP(0, AQa, BHa);                                                           \
    __builtin_amdgcn_s_setprio(0);                                                \
    RD_AQ(AQb, 1, rd0, _bo);                                                      \
    __builtin_amdgcn_s_barrier();                                                 \
    /* p1 */                                                                      \
    __builtin_amdgcn_s_setprio(1);                                                \
    MFMAP(1, AQb, BHa);                                                           \
    __builtin_amdgcn_s_setprio(0);                                                \
    RD_BH(BHb, rd1, _bo);                                                         \
    RD_AQ(AQa, 0, rd1, _bo);                                                      \
    __builtin_amdgcn_s_barrier();                                                 \
    /* p2 */                                                                      \
    __builtin_amdgcn_s_setprio(1);                                                \
    MFMAP(0, AQa, BHb);                                                           \
    __builtin_amdgcn_s_setprio(0);                                                \
    RD_AQ(AQb, 1, rd1, _bo);                                                      \
    STAGE(gB0p, 65536 + _bo, (KT) + 2);                                           \
    STAGE(gB1p, 65536 + _bo + 16384, (KT) + 2);                                   \
    asm volatile("s_waitcnt vmcnt(4)" ::: "memory");                              \
    __builtin_amdgcn_s_barrier();                                                 \
    /* p3 */                                                                      \
    __builtin_amdgcn_s_setprio(1);                                                \
    MFMAP(1, AQb, BHb);                                                           \
    __builtin_amdgcn_s_setprio(0);                                                \
    RD_AQ(AQa, 0, rd0, _bo1);                                                     \
    RD_BH(BHa, rd0, _bo1);                                                        \
    STAGE(gA0p, _bo, (KT) + 2);                                                   \
    STAGE(gA1p, _bo + 16384, (KT) + 2);                                           \
    __builtin_amdgcn_s_barrier();                                                 \
  } while (0)

__launch_bounds__(512, 2)
__global__ void lstm_gemm_kernel(const unsigned short* __restrict__ A,
                                 const unsigned short* __restrict__ Bp,
                                 const float* __restrict__ c_prev,
                                 const float* __restrict__ bxi, const float* __restrict__ bhi,
                                 const float* __restrict__ bxf, const float* __restrict__ bhf,
                                 const float* __restrict__ bxc, const float* __restrict__ bhc,
                                 const float* __restrict__ bxo, const float* __restrict__ bho,
                                 float* __restrict__ out) {
  __shared__ __align__(16) char lds[131072];

  // XCD-aware bijective swizzle (512 % 8 == 0)
  const int nwg = gridDim.x;
  int bid = blockIdx.x;
  int q = nwg >> 3;
  int wg = (bid & 7) * q + (bid >> 3);
  int bm = wg >> 4;          // 32 M-tiles
  int bn = wg & 15;          // 16 N-tiles

  int tid = threadIdx.x;
  int lane = tid & 63;
  int wid = tid >> 6;        // 8 waves
  int wm = wid >> 2;         // 2 M-wave rows (128 rows each)
  int wn = wid & 3;          // 4 N-wave cols (64 cols each)

  // staging addresses: per half-tile, wave covers 8 rows x 128B; pre-swizzled
  // global source (rule #21): linear LDS dest, src chunk XOR row&7, same XOR on read.
  int srow = lane >> 3;                 // row within 8-row stripe
  int schunk = (lane & 7) ^ srow;       // swizzled 16B chunk
  const unsigned short* gA0p = A  + (size_t)(bm * 256 + wid * 8 + srow) * K_DIM + schunk * 8;
  const unsigned short* gA1p = gA0p + (size_t)128 * K_DIM;
  const unsigned short* gB0p = Bp + (size_t)(bn * 256 + wid * 8 + srow) * K_DIM + schunk * 8;
  const unsigned short* gB1p = gB0p + (size_t)128 * K_DIM;

  // LDS read bases (byte ptrs); frag row&7 == lane&7 for all fragment rows.
  int c15 = lane & 15;
  int kl = lane >> 4;                   // k-group 0..3
  const char* ldsAr = lds + wm * 16384 + c15 * 128;
  const char* ldsBr = lds + 65536 + (wn >> 1) * 16384 + ((wn & 1) * 64 + c15) * 128;
  int rd0 = ((kl) ^ (lane & 7)) << 4;         // kk=0 chunk
  int rd1 = ((4 | kl) ^ (lane & 7)) << 4;     // kk=1 chunk

  f32x4 acc[8][4];
  f32x4 zero = {0.f, 0.f, 0.f, 0.f};
#pragma unroll
  for (int m = 0; m < 8; ++m)
#pragma unroll
    for (int n = 0; n < 4; ++n) acc[m][n] = zero;

  bf16x8 AQa[4], AQb[4];   // A-quarter ping/pong (4 m-frags x 1 kk each)
  bf16x8 BHa[4], BHb[4];   // B kk-half ping/pong (4 n-frags each)

  // ---- prologue: stage tile0 -> buf0, tile1 -> buf1 (16 loads);
  // vmcnt(8) -> buf0 landed; pre-read p0 operands. ----
  STAGE(gA0p, 0, 0);
  STAGE(gA1p, 16384, 0);
  STAGE(gB0p, 65536, 0);
  STAGE(gB1p, 65536 + 16384, 0);
  STAGE(gA0p, 32768, 1);
  STAGE(gA1p, 32768 + 16384, 1);
  STAGE(gB0p, 65536 + 32768, 1);
  STAGE(gB1p, 65536 + 32768 + 16384, 1);
  asm volatile("s_waitcnt vmcnt(8)" ::: "memory");
  __builtin_amdgcn_s_barrier();
  RD_AQ(AQa, 0, rd0, 0);
  RD_BH(BHa, rd0, 0);

#pragma unroll 1
  for (int kt = 0; kt < NKT; kt += 2) {
    KTILE(0, kt);
    KTILE(1, kt + 1);
  }

  // ---- fused LSTM epilogue: lane owns hidden unit h; acc[mi][g][j] = gate g ----
  int h = (bn * 4 + wn) * 16 + c15;
  float bi = bxi[h] + bhi[h];
  float bf_ = bxf[h] + bhf[h];
  float bc = bxc[h] + bhc[h];
  float bo = bxo[h] + bho[h];
  int row0 = bm * 256 + wm * 128 + kl * 4;
#pragma unroll
  for (int mi = 0; mi < 8; ++mi) {
#pragma unroll
    for (int j = 0; j < 4; ++j) {
      int r = row0 + mi * 16 + j;
      size_t off = (size_t)r * H_DIM + h;
      float zi = acc[mi][0][j] + bi;
      float zf = acc[mi][1][j] + bf_;
      float zc = acc[mi][2][j] + bc;
      float zo = acc[mi][3][j] + bo;
      float ig = 1.f / (1.f + __expf(-zi));
      float fg = 1.f / (1.f + __expf(-zf));
      float e2 = __expf(-2.f * zc);
      float gg = (1.f - e2) / (1.f + e2);       // tanh(zc)
      float og = 1.f / (1.f + __expf(-zo));
      float cp = c_prev[off];
      float cn = fg * cp + ig * gg;
      float e2c = __expf(-2.f * cn);
      float th = (1.f - e2c) / (1.f + e2c);     // tanh(cn)
      out[off] = og * th;                        // h_new
      out[(size_t)B_DIM * H_DIM + off] = cn;     // c_new
    }
  }
}

extern "C" void kernel_launch(void* const* d_in, const int* in_sizes, int n_in,
                              void* d_out, int out_size, void* d_ws, size_t ws_size,
                              hipStream_t stream) {
  const float* x      = (const float*)d_in[0];
  const float* h_prev = (const float*)d_in[1];
  const float* c_prev = (const float*)d_in[2];
  const float* Wxi = (const float*)d_in[3];
  const float* Whi = (const float*)d_in[4];
  const float* Wxf = (const float*)d_in[5];
  const float* Whf = (const float*)d_in[6];
  const float* Wxc = (const float*)d_in[7];
  const float* Whc = (const float*)d_in[8];
  const float* Wxo = (const float*)d_in[9];
  const float* Who = (const float*)d_in[10];
  const float* bxi = (const float*)d_in[11];
  const float* bhi = (const float*)d_in[12];
  const float* bxf = (const float*)d_in[13];
  const float* bhf = (const float*)d_in[14];
  const float* bxc = (const float*)d_in[15];
  const float* bhc = (const float*)d_in[16];
  const float* bxo = (const float*)d_in[17];
  const float* bho = (const float*)d_in[18];

  unsigned short* Abf = (unsigned short*)d_ws;                                      // 32 MiB
  unsigned short* Bbf = (unsigned short*)((char*)d_ws + (size_t)B_DIM * K_DIM * 2); // +16 MiB

  pack_A_kernel<<<2048, 256, 0, stream>>>(x, h_prev, Abf);
  pack_B_kernel<<<1024, 256, 0, stream>>>(Wxi, Whi, Wxf, Whf, Wxc, Whc, Wxo, Who, Bbf);
  lstm_gemm_kernel<<<512, 512, 0, stream>>>(Abf, Bbf, c_prev,
      bxi, bhi, bxf, bhf, bxc, bhc, bxo, bho, (float*)d_out);
}